// Round 15
// baseline (379.019 us; speedup 1.0000x reference)
//
#include <hip/hip_runtime.h>
#include <hip/hip_bf16.h>
#include <cstddef>

#define NN    10000
#define PP    12
#define EMAIN 160000
#define EREG  40000
#define ETOT  (EMAIN + 5 * EREG)
#define OUTD  256
#define HIDD  128

typedef __attribute__((ext_vector_type(8))) short bf16x8;
typedef __attribute__((ext_vector_type(4))) float f32x4;

// ---- workspace layout (float offsets) ----
enum : int {
  WS_PROBS    = 0,                       // 16
  WS_CNT      = 16,                      // 6*NN ints (in-degree per graph) [zeroed]
  WS_DEGR     = WS_CNT + 6 * NN,         // 5*NN floats (weighted src-degree) [zeroed]
  WS_ZERO_END = WS_DEGR + 5 * NN,
  WS_DINVM    = WS_ZERO_END,             // NN
  WS_DINV2M   = WS_DINVM + NN,           // NN
  WS_DINVR    = WS_DINV2M + NN,          // 5*NN
  WS_STARTS   = WS_DINVR + 5 * NN,       // 6*(NN+1) ints
  WS_CURSOR   = WS_STARTS + 6 * (NN + 1),// 6*NN ints
  WS_CSRS     = WS_CURSOR + 6 * NN,      // ETOT ints
  WS_CSRN     = WS_CSRS + ETOT,          // ETOT floats
  WS_AGGM     = WS_CSRN + ETOT,          // NN*48
  WS_TX1      = WS_AGGM + NN * 48,       // 5*NN*48
  WS_MCAT     = WS_TX1 + 5 * NN * 48,    // 24*OUTD (fp32)
  WS_BIASH    = WS_MCAT + 24 * OUTD,
  WS_AZ       = WS_BIASH + OUTD,         // 4*OUTD (Az,Ar,Ah contiguous)
  WS_AR       = WS_AZ + 4 * OUTD,
  WS_AH       = WS_AR + 4 * OUTD,
  WS_BZ       = WS_AH + 4 * OUTD,
  WS_BR       = WS_BZ + OUTD,
  WS_BH       = WS_BR + OUTD,
  WS_MCT      = WS_BH + OUTD,            // 256*32 bf16
  WS_WZT      = WS_MCT + 4096,           // 256*288 bf16 each
  WS_WRT      = WS_WZT + 36864,
  WS_WHT      = WS_WRT + 36864,
  WS_TOTAL    = WS_WHT + 36864
};

__device__ __forceinline__ float sigm(float v) { return 1.f / (1.f + __expf(-v)); }
__device__ __forceinline__ float tanh_f(float v) { float e = __expf(2.f * v); return 1.f - 2.f / (e + 1.f); }

// native HW bf16 conversions (v_cvt_pk_bf16_f32); __hip_bfloat16/2 are not
// trivially copyable -> __builtin_memcpy, not bit_cast (round-12 lesson)
__device__ __forceinline__ short bf16c(float v) {
  __hip_bfloat16 h = __float2bfloat16(v);
  short r;
  __builtin_memcpy(&r, &h, sizeof(r));
  return r;
}
__device__ __forceinline__ unsigned cvt2(float a, float b) {
  __hip_bfloat162 h2 = __float22bfloat162_rn(make_float2(a, b));
  unsigned r;
  __builtin_memcpy(&r, &h2, sizeof(r));
  return r;
}
__device__ __forceinline__ float upk_lo(unsigned u) { return __uint_as_float(u << 16); }
__device__ __forceinline__ float upk_hi(unsigned u) { return __uint_as_float(u & 0xffff0000u); }

__device__ __forceinline__ const int* sel_i(int r, const int* a, const int* b, const int* c, const int* d, const int* e) {
  return r == 0 ? a : r == 1 ? b : r == 2 ? c : r == 3 ? d : e;
}
__device__ __forceinline__ const float* sel_f(int r, const float* a, const float* b, const float* c, const float* d, const float* e) {
  return r == 0 ? a : r == 1 ? b : r == 2 ? c : r == 3 ? d : e;
}

__global__ void probs_kernel(const float* __restrict__ att, float* __restrict__ probs) {
  if (threadIdx.x == 0 && blockIdx.x == 0) {
    float m = att[0];
    for (int i = 1; i < PP; ++i) m = fmaxf(m, att[i]);
    float e[PP]; float s = 0.f;
    for (int i = 0; i < PP; ++i) { e[i] = __expf(att[i] - m); s += e[i]; }
    float inv = 1.f / s;
    for (int i = 0; i < PP; ++i) probs[i] = e[i] * inv;
  }
}

// in-degree counts (per graph, by dst) + weighted src-degree for cheb
__global__ void count_kernel(const int* __restrict__ eim,
    const int* e0, const int* e1, const int* e2, const int* e3, const int* e4,
    const float* w0, const float* w1, const float* w2, const float* w3, const float* w4,
    int* __restrict__ cnt, float* __restrict__ degr) {
  int g = blockIdx.x * 256 + threadIdx.x;
  if (g >= ETOT) return;
  if (g < EMAIN) {
    atomicAdd(&cnt[eim[EMAIN + g]], 1);
  } else {
    int q = g - EMAIN;
    int r = q / EREG;
    int e = q - r * EREG;
    const int* ei = sel_i(r, e0, e1, e2, e3, e4);
    const float* w = sel_f(r, w0, w1, w2, w3, w4);
    atomicAdd(&cnt[(1 + r) * NN + ei[EREG + e]], 1);
    atomicAdd(&degr[r * NN + ei[e]], w[e]);
  }
}

__global__ void dinv_kernel(const int* __restrict__ cnt, const float* __restrict__ degr,
    float* __restrict__ dinvm, float* __restrict__ dinv2m, float* __restrict__ dinvr) {
  int g = blockIdx.x * 256 + threadIdx.x;
  if (g >= 6 * NN) return;
  if (g < NN) {
    float c = (float)(cnt[g] + 1);
    dinvm[g] = rsqrtf(c);
    dinv2m[g] = 1.0f / c;
  } else {
    int q = g - NN;
    float dv = degr[q];
    dinvr[q] = dv > 0.f ? rsqrtf(fmaxf(dv, 1e-12f)) : 0.f;
  }
}

// exclusive prefix sum per graph (block b = graph b); writes starts (+sentinel) and cursor
__global__ __launch_bounds__(1024) void scan_kernel(const int* __restrict__ cnt,
    int* __restrict__ starts, int* __restrict__ cursor) {
  const int b = blockIdx.x;
  const int t = threadIdx.x;
  const int base = (b == 0) ? 0 : EMAIN + (b - 1) * EREG;
  const int Eg = (b == 0) ? EMAIN : EREG;
  int loc[10];
  int s = 0;
#pragma unroll
  for (int c = 0; c < 10; ++c) {
    int idx = t * 10 + c;
    int v = (idx < NN) ? cnt[b * NN + idx] : 0;
    loc[c] = s;
    s += v;
  }
  __shared__ int sm[1024];
  sm[t] = s;
  __syncthreads();
  for (int off = 1; off < 1024; off <<= 1) {
    int v = (t >= off) ? sm[t - off] : 0;
    __syncthreads();
    sm[t] += v;
    __syncthreads();
  }
  int ex = base + (t > 0 ? sm[t - 1] : 0);
#pragma unroll
  for (int c = 0; c < 10; ++c) {
    int idx = t * 10 + c;
    if (idx < NN) {
      int v = ex + loc[c];
      starts[b * (NN + 1) + idx] = v;
      cursor[b * NN + idx] = v;
    }
  }
  if (t == 0) starts[b * (NN + 1) + NN] = base + Eg;
}

// fill CSR: per edge, compute norm and place (src, norm) in dst's slot
__global__ void fill_kernel(const int* __restrict__ eim,
    const int* e0, const int* e1, const int* e2, const int* e3, const int* e4,
    const float* w0, const float* w1, const float* w2, const float* w3, const float* w4,
    const float* __restrict__ dinvm, const float* __restrict__ dinvr,
    int* __restrict__ cursor, int* __restrict__ csrs, float* __restrict__ csrn) {
  int g = blockIdx.x * 256 + threadIdx.x;
  if (g >= ETOT) return;
  int s, gi; float nv;
  if (g < EMAIN) {
    s = eim[g];
    int d = eim[EMAIN + g];
    nv = dinvm[s] * dinvm[d];
    gi = d;
  } else {
    int q = g - EMAIN;
    int r = q / EREG;
    int e = q - r * EREG;
    const int* ei = sel_i(r, e0, e1, e2, e3, e4);
    const float* w = sel_f(r, w0, w1, w2, w3, w4);
    s = ei[e];
    int d = ei[EREG + e];
    nv = -(dinvr[r * NN + s] * w[e] * dinvr[r * NN + d]);
    gi = (1 + r) * NN + d;
  }
  int pos = atomicAdd(&cursor[gi], 1);
  csrs[pos] = s;
  csrn[pos] = nv;
}

// gather: thread per (graph, node, i in 0..47); no atomics, coalesced x reads
__global__ void gather_kernel(const float* __restrict__ x,
    const int* __restrict__ starts, const int* __restrict__ csrs,
    const float* __restrict__ csrn,
    float* __restrict__ aggm, float* __restrict__ tx1) {
  int id = blockIdx.x * 256 + threadIdx.x;   // grid = 6*NN*48/256 exactly
  int gi = id / 48;
  int i = id - gi * 48;
  int g = gi / NN;
  int n = gi - g * NN;
  int st = starts[g * (NN + 1) + n];
  int en = starts[g * (NN + 1) + n + 1];
  float acc = 0.f;
  for (int e = st; e < en; ++e)
    acc += csrn[e] * x[(size_t)csrs[e] * 48 + i];
  if (g == 0) aggm[n * 48 + i] = acc;
  else        tx1[(size_t)((g - 1) * NN + n) * 48 + i] = acc;
}

// parallel fold of small matrices (fp32). 128 blocks x 256 thr; see round-6 notes.
__global__ __launch_bounds__(256) void prep_parallel_kernel(
    const float* __restrict__ W0, const float* __restrict__ W1, const float* __restrict__ chebb,
    const float* __restrict__ lcW, const float* __restrict__ lcb,
    const float* __restrict__ gzW, const float* __restrict__ gzb,
    const float* __restrict__ grW, const float* __restrict__ grb,
    const float* __restrict__ ghW, const float* __restrict__ ghb,
    const float* __restrict__ lzW, const float* __restrict__ lzb,
    const float* __restrict__ lrW, const float* __restrict__ lrb,
    const float* __restrict__ lhW, const float* __restrict__ lhb,
    float* __restrict__ ws) {
  const int b = blockIdx.x;
  const int tid = threadIdx.x;
  const int jj = tid >> 5;
  const int kk = tid & 31;

  if (b < 32) {
    const int j = b * 8 + jj;
    float m0[4] = {0, 0, 0, 0};
    float m1[5][4] = {};
    float bhh = 0.f;
    for (int k = kk; k < OUTD; k += 32) {
      float w1v[4];
#pragma unroll
      for (int f = 0; f < 4; ++f) w1v[f] = W1[f * OUTD + k];
      float s5 = 0.f;
#pragma unroll
      for (int r = 0; r < 5; ++r) {
        float wv = lcW[(r * OUTD + k) * OUTD + j];
        s5 += wv;
#pragma unroll
        for (int f = 0; f < 4; ++f) m1[r][f] += w1v[f] * wv;
      }
#pragma unroll
      for (int f = 0; f < 4; ++f) m0[f] += W0[f * OUTD + k] * s5;
      bhh += chebb[k] * s5;
    }
#pragma unroll
    for (int off = 16; off >= 1; off >>= 1) {
#pragma unroll
      for (int f = 0; f < 4; ++f) m0[f] += __shfl_xor(m0[f], off);
#pragma unroll
      for (int r = 0; r < 5; ++r)
#pragma unroll
        for (int f = 0; f < 4; ++f) m1[r][f] += __shfl_xor(m1[r][f], off);
      bhh += __shfl_xor(bhh, off);
    }
    if (kk == 0) {
      float* Mcat = ws + WS_MCAT;
#pragma unroll
      for (int f = 0; f < 4; ++f) Mcat[f * OUTD + j] = m0[f];
#pragma unroll
      for (int r = 0; r < 5; ++r)
#pragma unroll
        for (int f = 0; f < 4; ++f) Mcat[(4 + 4 * r + f) * OUTD + j] = m1[r][f];
      ws[WS_BIASH + j] = bhh + lcb[j];
    }
  } else {
    const int g = (b - 32) >> 5;
    const int j = ((b - 32) & 31) * 8 + jj;
    const float* gW = g == 0 ? gzW : g == 1 ? grW : ghW;
    const float* gb = g == 0 ? gzb : g == 1 ? grb : ghb;
    const float* lW = g == 0 ? lzW : g == 1 ? lrW : lhW;
    const float* lb = g == 0 ? lzb : g == 1 ? lrb : lhb;
    float a[4] = {0, 0, 0, 0};
    float vb = 0.f;
    for (int k = kk; k < OUTD; k += 32) {
      float wv = lW[k * OUTD + j];
#pragma unroll
      for (int f = 0; f < 4; ++f) a[f] += gW[f * OUTD + k] * wv;
      vb += gb[k] * wv;
    }
#pragma unroll
    for (int off = 16; off >= 1; off >>= 1) {
#pragma unroll
      for (int f = 0; f < 4; ++f) a[f] += __shfl_xor(a[f], off);
      vb += __shfl_xor(vb, off);
    }
    if (kk == 0) {
      float* A = ws + WS_AZ + g * (4 * OUTD);
#pragma unroll
      for (int f = 0; f < 4; ++f) A[f * OUTD + j] = a[f];
      ws[WS_BZ + g * OUTD + j] = vb + lb[j];
    }
  }
}

// build transposed bf16 weight panels (see round-4 notes)
__global__ void prepT_kernel(
    const float* __restrict__ lzW, const float* __restrict__ lrW, const float* __restrict__ lhW,
    float* __restrict__ ws) {
  int bx = blockIdx.x;
  int g = bx >> 8;
  int j = bx & 255;
  if (g < 3) {
    const float* Wsrc = g == 0 ? lzW : g == 1 ? lrW : lhW;
    const float* Afold = ws + WS_AZ + g * (4 * OUTD);
    short* dst = (short*)(ws + (g == 0 ? WS_WZT : g == 1 ? WS_WRT : WS_WHT));
    for (int k = threadIdx.x; k < 288; k += 128) {
      float v = 0.f;
      if (k < 256) v = Wsrc[(256 + k) * OUTD + j];
      else if (k >= 280 && k < 284) v = Afold[(k - 280) * OUTD + j];
      dst[j * 288 + k] = bf16c(v);
    }
  } else {
    const float* Mcat = ws + WS_MCAT;
    short* mct = (short*)(ws + WS_MCT);
    for (int k = threadIdx.x; k < 32; k += 128) {
      float v = (k < 24) ? Mcat[k * OUTD + j] : 0.f;
      mct[j * 32 + k] = bf16c(v);
    }
  }
}

#define GATE_MFMA(WT) do {                                                          \
  _Pragma("unroll") for (int m_ = 0; m_ < 6; ++m_)                                  \
    _Pragma("unroll") for (int nt_ = 0; nt_ < 2; ++nt_)                             \
      acc[m_][nt_] = (f32x4){0.f, 0.f, 0.f, 0.f};                                   \
  _Pragma("unroll") for (int ks_ = 0; ks_ < 9; ++ks_) {                             \
    bf16x8 bfr_[2];                                                                 \
    _Pragma("unroll") for (int nt_ = 0; nt_ < 2; ++nt_)                             \
      bfr_[nt_] = *(const bf16x8*)((WT) + (size_t)(wcol + nt_ * 16 + lr) * 288 + ks_ * 32 + 8 * lg); \
    _Pragma("unroll") for (int m_ = 0; m_ < 6; ++m_) {                              \
      bf16x8 af_ = *(const bf16x8*)(&As[m_ * 16 + lr][ks_ * 32 + 8 * lg]);          \
      _Pragma("unroll") for (int nt_ = 0; nt_ < 2; ++nt_)                           \
        acc[m_][nt_] = __builtin_amdgcn_mfma_f32_16x16x32_bf16(af_, bfr_[nt_], acc[m_][nt_], 0, 0, 0); \
    }                                                                               \
  }                                                                                 \
} while (0)

// fused MFMA GRU: 8 nodes x 12 periods = 96 rows per block; 8 waves x 32 cols
__global__ __launch_bounds__(512, 2) void gru_mfma_kernel(
    const float* __restrict__ x,
    const float* __restrict__ ws,
    float* __restrict__ Hout) {
  const int n0 = blockIdx.x * 8;
  const int t = threadIdx.x;
  const int w = t >> 6;
  const int l = t & 63;
  const int lr = l & 15;
  const int lg = l >> 4;
  const int wcol = w * 32;

  __shared__ __align__(16) short As[96][296];   // rows: p*8+nl ; k: 0..255 h/hR, 256..287 U/aggx

  const float* aggm   = ws + WS_AGGM;
  const float* tx1    = ws + WS_TX1;
  const float* dinv2m = ws + WS_DINV2M;
  const float* biash  = ws + WS_BIASH;
  const float* bz     = ws + WS_BZ;
  const float* br     = ws + WS_BR;
  const float* bh     = ws + WS_BH;
  const float* probs  = ws + WS_PROBS;
  const short* McT = (const short*)(ws + WS_MCT);
  const short* WzT = (const short*)(ws + WS_WZT);
  const short* WrT = (const short*)(ws + WS_WRT);
  const short* WhT = (const short*)(ws + WS_WHT);

  // ---- stage U (bf16) into As[row][256..287]
  for (int idx = t; idx < 96 * 32; idx += 512) {
    int row = idx >> 5, s = idx & 31;
    int p = row >> 3, nl = row & 7, n = n0 + nl;
    float v = 0.f;
    if (s < 4) {
      v = x[n * 48 + s * 12 + p];
    } else if (s < 24) {
      int q = s - 4; int r = q >> 2; int f = q & 3;
      v = tx1[(size_t)(r * NN + n) * 48 + f * 12 + p];
    } else if (s < 28) {
      int f = s - 24;
      v = aggm[n * 48 + f * 12 + p] + dinv2m[n] * x[n * 48 + f * 12 + p];
    }
    As[row][256 + s] = bf16c(v);
  }
  __syncthreads();

  f32x4 acc[6][2];

  // ---- h = leaky_relu(U @ Mcat + biash)
  {
    bf16x8 bm[2];
#pragma unroll
    for (int nt = 0; nt < 2; ++nt)
      bm[nt] = *(const bf16x8*)(McT + (size_t)(wcol + nt * 16 + lr) * 32 + 8 * lg);
    const f32x4 zf = {0.f, 0.f, 0.f, 0.f};
#pragma unroll
    for (int m = 0; m < 6; ++m) {
      bf16x8 af = *(const bf16x8*)(&As[m * 16 + lr][256 + 8 * lg]);
#pragma unroll
      for (int nt = 0; nt < 2; ++nt)
        acc[m][nt] = __builtin_amdgcn_mfma_f32_16x16x32_bf16(af, bm[nt], zf, 0, 0, 0);
    }
  }
  unsigned hp[6][2][2];
#pragma unroll
  for (int nt = 0; nt < 2; ++nt) {
    int col = wcol + nt * 16 + lr;
    float bb = biash[col];
#pragma unroll
    for (int m = 0; m < 6; ++m) {
      f32x4 a = acc[m][nt];
      int rmb = m * 16 + 4 * lg;
      float v0 = a[0] + bb; v0 = fmaxf(v0, 0.01f * v0);   // leaky_relu
      float v1 = a[1] + bb; v1 = fmaxf(v1, 0.01f * v1);
      float v2 = a[2] + bb; v2 = fmaxf(v2, 0.01f * v2);
      float v3 = a[3] + bb; v3 = fmaxf(v3, 0.01f * v3);
      unsigned u01 = cvt2(v0, v1);
      unsigned u23 = cvt2(v2, v3);
      As[rmb + 0][col] = (short)(u01 & 0xffffu);
      As[rmb + 1][col] = (short)(u01 >> 16);
      As[rmb + 2][col] = (short)(u23 & 0xffffu);
      As[rmb + 3][col] = (short)(u23 >> 16);
      hp[m][nt][0] = u01;
      hp[m][nt][1] = u23;
    }
  }
  __syncthreads();

  // ---- Z
  GATE_MFMA(WzT);
  unsigned zp[6][2][2];
#pragma unroll
  for (int nt = 0; nt < 2; ++nt) {
    float bb = bz[wcol + nt * 16 + lr];
#pragma unroll
    for (int m = 0; m < 6; ++m) {
      f32x4 a = acc[m][nt];
      zp[m][nt][0] = cvt2(sigm(a[0] + bb), sigm(a[1] + bb));
      zp[m][nt][1] = cvt2(sigm(a[2] + bb), sigm(a[3] + bb));
    }
  }

  // ---- R ; overwrite As k<256 with h*R
  GATE_MFMA(WrT);
  __syncthreads();
#pragma unroll
  for (int nt = 0; nt < 2; ++nt) {
    int col = wcol + nt * 16 + lr;
    float bb = br[col];
#pragma unroll
    for (int m = 0; m < 6; ++m) {
      f32x4 a = acc[m][nt];
      int rmb = m * 16 + 4 * lg;
      unsigned u01 = cvt2(upk_lo(hp[m][nt][0]) * sigm(a[0] + bb),
                          upk_hi(hp[m][nt][0]) * sigm(a[1] + bb));
      unsigned u23 = cvt2(upk_lo(hp[m][nt][1]) * sigm(a[2] + bb),
                          upk_hi(hp[m][nt][1]) * sigm(a[3] + bb));
      As[rmb + 0][col] = (short)(u01 & 0xffffu);
      As[rmb + 1][col] = (short)(u01 >> 16);
      As[rmb + 2][col] = (short)(u23 & 0xffffu);
      As[rmb + 3][col] = (short)(u23 >> 16);
    }
  }
  __syncthreads();

  // ---- Ht ; final combine + attention-weighted p-reduction
  GATE_MFMA(WhT);
  float pr[6];
#pragma unroll
  for (int m = 0; m < 6; ++m) pr[m] = probs[2 * m + (lg >> 1)];
  float wsum[2][4];
#pragma unroll
  for (int nt = 0; nt < 2; ++nt)
#pragma unroll
    for (int q = 0; q < 4; ++q) wsum[nt][q] = 0.f;
#pragma unroll
  for (int nt = 0; nt < 2; ++nt) {
    int col = wcol + nt * 16 + lr;
    float bb = bh[col];
#pragma unroll
    for (int m = 0; m < 6; ++m) {
      f32x4 a = acc[m][nt];
      float hv0 = upk_lo(hp[m][nt][0]), hv1 = upk_hi(hp[m][nt][0]);
      float hv2 = upk_lo(hp[m][nt][1]), hv3 = upk_hi(hp[m][nt][1]);
      float zv0 = upk_lo(zp[m][nt][0]), zv1 = upk_hi(zp[m][nt][0]);
      float zv2 = upk_lo(zp[m][nt][1]), zv3 = upk_hi(zp[m][nt][1]);
      float t0 = tanh_f(a[0] + bb);
      float t1 = tanh_f(a[1] + bb);
      float t2 = tanh_f(a[2] + bb);
      float t3 = tanh_f(a[3] + bb);
      // z*h + (1-z)*t  ==  t + z*(h-t)
      wsum[nt][0] += pr[m] * (t0 + zv0 * (hv0 - t0));
      wsum[nt][1] += pr[m] * (t1 + zv1 * (hv1 - t1));
      wsum[nt][2] += pr[m] * (t2 + zv2 * (hv2 - t2));
      wsum[nt][3] += pr[m] * (t3 + zv3 * (hv3 - t3));
    }
  }
#pragma unroll
  for (int nt = 0; nt < 2; ++nt)
#pragma unroll
    for (int q = 0; q < 4; ++q) {
      float tot = wsum[nt][q] + __shfl_xor(wsum[nt][q], 32);
      if (lg < 2)
        Hout[(size_t)(n0 + 4 * lg + q) * OUTD + wcol + nt * 16 + lr] = tot;
    }
}

// o = relu(relu(H) @ out1_W + b1) @ out2_W + b2 ; 8 nodes per block
__global__ __launch_bounds__(128) void head_kernel(
    const float* __restrict__ H,
    const float* __restrict__ W1, const float* __restrict__ b1,
    const float* __restrict__ W2, const float* __restrict__ b2,
    float* __restrict__ o) {
  const int n0 = blockIdx.x * 8;
  const int t = threadIdx.x;
  __shared__ float hr[8][OUTD];
  __shared__ float hid[8][130];
  for (int idx = t; idx < 8 * OUTD; idx += 128) {
    int r = idx >> 8, c = idx & 255;
    float v = H[(n0 + r) * OUTD + c];
    hr[r][c] = v > 0.f ? v : 0.f;
  }
  __syncthreads();
  float acc[8];
  float bb = b1[t];
#pragma unroll
  for (int r = 0; r < 8; ++r) acc[r] = bb;
  for (int k = 0; k < OUTD; ++k) {
    float w = W1[k * HIDD + t];
#pragma unroll
    for (int r = 0; r < 8; ++r) acc[r] += hr[r][k] * w;
  }
#pragma unroll
  for (int r = 0; r < 8; ++r) hid[r][t] = acc[r] > 0.f ? acc[r] : 0.f;
  __syncthreads();
  if (t < 96) {
    int r = t / 12, dd = t - r * 12;
    float a = b2[dd];
    for (int k = 0; k < HIDD; ++k) a += hid[r][k] * W2[k * 12 + dd];
    o[(n0 + r) * 12 + dd] = a;
  }
}

extern "C" void kernel_launch(void* const* d_in, const int* in_sizes, int n_in,
                              void* d_out, int out_size, void* d_ws, size_t ws_size,
                              hipStream_t stream) {
  (void)in_sizes; (void)n_in; (void)out_size; (void)ws_size;
  const float* x    = (const float*)d_in[0];
  const int*   eim  = (const int*)d_in[1];
  const int*   ei0  = (const int*)d_in[2];
  const float* ew0  = (const float*)d_in[3];
  const int*   ei1  = (const int*)d_in[4];
  const float* ew1  = (const float*)d_in[5];
  const int*   ei2  = (const int*)d_in[6];
  const float* ew2  = (const float*)d_in[7];
  const int*   ei3  = (const int*)d_in[8];
  const float* ew3  = (const float*)d_in[9];
  const int*   ei4  = (const int*)d_in[10];
  const float* ew4  = (const float*)d_in[11];
  const float* chebW0 = (const float*)d_in[12];
  const float* chebW1 = (const float*)d_in[13];
  const float* chebb  = (const float*)d_in[14];
  const float* lcW  = (const float*)d_in[15];
  const float* lcb  = (const float*)d_in[16];
  const float* att  = (const float*)d_in[17];
  const float* gzW  = (const float*)d_in[18];
  const float* gzb  = (const float*)d_in[19];
  const float* grW  = (const float*)d_in[20];
  const float* grb  = (const float*)d_in[21];
  const float* ghW  = (const float*)d_in[22];
  const float* ghb  = (const float*)d_in[23];
  const float* lzW  = (const float*)d_in[24];
  const float* lzb  = (const float*)d_in[25];
  const float* lrW  = (const float*)d_in[26];
  const float* lrb  = (const float*)d_in[27];
  const float* lhW  = (const float*)d_in[28];
  const float* lhb  = (const float*)d_in[29];
  const float* o1W  = (const float*)d_in[30];
  const float* o1b  = (const float*)d_in[31];
  const float* o2W  = (const float*)d_in[32];
  const float* o2b  = (const float*)d_in[33];

  float* ws = (float*)d_ws;
  float* out = (float*)d_out;
  float* o_out = out;                 // (N,12) flat
  float* H_out = out + NN * 12;       // (N,256) flat

  int*   cnt    = (int*)(ws + WS_CNT);
  float* degr   = ws + WS_DEGR;
  int*   starts = (int*)(ws + WS_STARTS);
  int*   cursor = (int*)(ws + WS_CURSOR);
  int*   csrs   = (int*)(ws + WS_CSRS);
  float* csrn   = ws + WS_CSRN;

  (void)hipMemsetAsync(ws, 0, (size_t)WS_ZERO_END * sizeof(float), stream);
  probs_kernel<<<1, 64, 0, stream>>>(att, ws + WS_PROBS);
  count_kernel<<<(ETOT + 255) / 256, 256, 0, stream>>>(
      eim, ei0, ei1, ei2, ei3, ei4, ew0, ew1, ew2, ew3, ew4, cnt, degr);
  dinv_kernel<<<(6 * NN + 255) / 256, 256, 0, stream>>>(
      cnt, degr, ws + WS_DINVM, ws + WS_DINV2M, ws + WS_DINVR);
  scan_kernel<<<6, 1024, 0, stream>>>(cnt, starts, cursor);
  fill_kernel<<<(ETOT + 255) / 256, 256, 0, stream>>>(
      eim, ei0, ei1, ei2, ei3, ei4, ew0, ew1, ew2, ew3, ew4,
      ws + WS_DINVM, ws + WS_DINVR, cursor, csrs, csrn);
  gather_kernel<<<(6 * NN * 48) / 256, 256, 0, stream>>>(
      x, starts, csrs, csrn, ws + WS_AGGM, ws + WS_TX1);
  prep_parallel_kernel<<<128, 256, 0, stream>>>(
      chebW0, chebW1, chebb, lcW, lcb,
      gzW, gzb, grW, grb, ghW, ghb,
      lzW, lzb, lrW, lrb, lhW, lhb,
      ws);
  prepT_kernel<<<1024, 128, 0, stream>>>(lzW, lrW, lhW, ws);
  gru_mfma_kernel<<<NN / 8, 512, 0, stream>>>(x, ws, H_out);
  head_kernel<<<NN / 8, 128, 0, stream>>>(H_out, o1W, o1b, o2W, o2b, o_out);
}